// Round 8
// baseline (176.830 us; speedup 1.0000x reference)
//
#include <hip/hip_runtime.h>
#include <hip/hip_fp16.h>

// GCN 2-layer forward. CSR via two-phase dst-sort (coalesced writes),
// MFMA fp16 GEMMs (fp32 accum), fp16 message tables, gather aggregation
// with packed-fp16 accumulate + 32-bit voffset addressing + 4x unroll.

#define CHUNK 4096
#define BCAP  4096
#define NB_PAD 1024

typedef _Float16 f16x8 __attribute__((ext_vector_type(8)));
typedef float f32x4 __attribute__((ext_vector_type(4)));

__device__ __forceinline__ unsigned int pack2(float a, float b) {
  __half2 h = __floats2half2_rn(a, b);
  return *reinterpret_cast<unsigned int*>(&h);
}

__global__ __launch_bounds__(256) void initcur_kernel(int* __restrict__ bcursor,
                                                      int nb) {
  int i = blockIdx.x * 256 + threadIdx.x;
  if (i < nb) bcursor[i] = i * BCAP;
}

// Phase 1: group edges by bucket b = dst>>7 into bucket-major ebuck.
__global__ __launch_bounds__(256) void chunksort_kernel(
    const int* __restrict__ src, const int* __restrict__ dst,
    int* __restrict__ bcursor, int* __restrict__ ebuck, int nE, int nb) {
  __shared__ int hist[NB_PAD];
  __shared__ int loff[NB_PAD];
  __shared__ int gbase[NB_PAD];
  __shared__ int lcur[NB_PAD];
  __shared__ int part[256];
  __shared__ int srec[CHUNK];
  __shared__ int saddr[CHUNK];
  const int t = threadIdx.x;
  const int e0 = blockIdx.x * CHUNK;
  const int n = min(CHUNK, nE - e0);
#pragma unroll
  for (int i = t; i < NB_PAD; i += 256) hist[i] = 0;
  __syncthreads();
  for (int i = t; i < n; i += 256) atomicAdd(&hist[dst[e0 + i] >> 7], 1);
  __syncthreads();
  int h0 = hist[4 * t], h1 = hist[4 * t + 1], h2 = hist[4 * t + 2], h3 = hist[4 * t + 3];
  part[t] = h0 + h1 + h2 + h3;
  __syncthreads();
  for (int off = 1; off < 256; off <<= 1) {
    int v = (t >= off) ? part[t - off] : 0;
    __syncthreads();
    part[t] += v;
    __syncthreads();
  }
  int base = (t == 0) ? 0 : part[t - 1];
  loff[4 * t] = base;
  loff[4 * t + 1] = base + h0;
  loff[4 * t + 2] = base + h0 + h1;
  loff[4 * t + 3] = base + h0 + h1 + h2;
  __syncthreads();
  for (int b = t; b < nb; b += 256) {
    int c = hist[b];
    gbase[b] = c ? atomicAdd(&bcursor[b], c) : 0;
    lcur[b] = loff[b];
  }
  __syncthreads();
  for (int i = t; i < n; i += 256) {
    int d = dst[e0 + i];
    int b = d >> 7;
    int p = atomicAdd(&lcur[b], 1);
    srec[p] = src[e0 + i] | ((d & 127) << 17);
    saddr[p] = gbase[b] + (p - loff[b]);
  }
  __syncthreads();
  for (int i = t; i < n; i += 256) ebuck[saddr[i]] = srec[i];
}

__global__ __launch_bounds__(1024) void bscan_kernel(const int* __restrict__ bcursor,
                                                     int* __restrict__ bbase, int nb) {
  __shared__ int part[1024];
  const int t = threadIdx.x;
  int c = (t < nb) ? (bcursor[t] - t * BCAP) : 0;
  part[t] = c;
  __syncthreads();
  for (int off = 1; off < 1024; off <<= 1) {
    int v = (t >= off) ? part[t - off] : 0;
    __syncthreads();
    part[t] += v;
    __syncthreads();
  }
  if (t < nb) bbase[t] = part[t] - c;  // exclusive
}

// Phase 2: per-bucket counting sort -> fully dst-sorted esrc + rowptr + dinv.
__global__ __launch_bounds__(256) void bucketsort_kernel(
    const int* __restrict__ ebuck, const int* __restrict__ bcursor,
    const int* __restrict__ bbase, int* __restrict__ esrc,
    int* __restrict__ rowptr, float* __restrict__ dinv, int N, int E, int nb) {
  __shared__ int hist[128];
  __shared__ int sc[128];
  __shared__ int rowcur[128];
  __shared__ int ssrc[BCAP];
  const int t = threadIdx.x;
  const int bk = blockIdx.x;
  const int base = bk * BCAP;
  const int cnt = bcursor[bk] - base;
  const int gb = bbase[bk];
  if (t < 128) hist[t] = 0;
  __syncthreads();
  for (int i = t; i < cnt; i += 256)
    atomicAdd(&hist[(ebuck[base + i] >> 17) & 127], 1);
  __syncthreads();
  if (t < 128) sc[t] = hist[t];
  __syncthreads();
  for (int off = 1; off < 128; off <<= 1) {
    int v = 0;
    if (t < 128 && t >= off) v = sc[t - off];
    __syncthreads();
    if (t < 128) sc[t] += v;
    __syncthreads();
  }
  if (t < 128) {
    int excl = (t == 0) ? 0 : sc[t - 1];
    rowcur[t] = excl;
    int node = bk * 128 + t;
    if (node < N) {
      rowptr[node] = gb + excl;
      dinv[node] = rsqrtf((float)hist[t] + 1.0f);
    }
  }
  if (bk == nb - 1 && t == 0) rowptr[N] = E;
  __syncthreads();
  for (int i = t; i < cnt; i += 256) {
    int rec = ebuck[base + i];
    int p = atomicAdd(&rowcur[(rec >> 17) & 127], 1);
    ssrc[p] = rec & 0x1FFFF;
  }
  __syncthreads();
  for (int i = t; i < cnt; i += 256) esrc[gb + i] = ssrc[i];
}

// H[N,64](fp16) = (X[N,K] @ W[K,64]) * dinv[row], via mfma_f32_16x16x32_f16.
template <int K, bool IN_HALF>
__global__ __launch_bounds__(256) void gemm_mfma(const void* __restrict__ Xin,
                                                 const float* __restrict__ W,
                                                 const float* __restrict__ dinv,
                                                 __half* __restrict__ H, int N) {
  __shared__ __align__(16) unsigned char sA[128 * K * 2];
  __shared__ __align__(16) unsigned char sB[64 * K * 2];
  const int t = threadIdx.x;
  const int brow = blockIdx.x * 128;
  constexpr int CH = K / 8;
  for (int idx = t; idx < 128 * CH; idx += 256) {
    int r = idx / CH, c = idx - r * CH;
    int row = brow + r;
    if (row >= N) row = N - 1;
    unsigned int off = (unsigned int)((r * K + c * 8) * 2) ^ ((r & 7) << 4);
    uint4 pk;
    if constexpr (IN_HALF) {
      pk = *reinterpret_cast<const uint4*>((const __half*)Xin + (size_t)row * K + c * 8);
    } else {
      const float4* xp =
          reinterpret_cast<const float4*>((const float*)Xin + (size_t)row * K + c * 8);
      float4 f0 = xp[0], f1 = xp[1];
      pk.x = pack2(f0.x, f0.y);
      pk.y = pack2(f0.z, f0.w);
      pk.z = pack2(f1.x, f1.y);
      pk.w = pack2(f1.z, f1.w);
    }
    *reinterpret_cast<uint4*>(sA + off) = pk;
  }
  for (int idx = t; idx < K * 64; idx += 256) {
    int k = idx >> 6, n = idx & 63;
    __half h = __float2half_rn(W[idx]);
    unsigned int off = (unsigned int)((n * K + k) * 2) ^ ((n & 7) << 4);
    *reinterpret_cast<unsigned short*>(sB + off) =
        *reinterpret_cast<unsigned short*>(&h);
  }
  __syncthreads();

  const int wv = t >> 6, l = t & 63;
  const int lr = l & 15;
  const int lk = (l >> 4) * 8;
  f32x4 acc[2][4] = {};
#pragma unroll
  for (int ks = 0; ks < K / 32; ++ks) {
    f16x8 af[2], bf[4];
#pragma unroll
    for (int m = 0; m < 2; ++m) {
      int r = wv * 32 + m * 16 + lr;
      unsigned int off = (unsigned int)((r * K + ks * 32 + lk) * 2) ^ ((r & 7) << 4);
      af[m] = *reinterpret_cast<const f16x8*>(sA + off);
    }
#pragma unroll
    for (int n = 0; n < 4; ++n) {
      int cc = n * 16 + lr;
      unsigned int off = (unsigned int)((cc * K + ks * 32 + lk) * 2) ^ ((cc & 7) << 4);
      bf[n] = *reinterpret_cast<const f16x8*>(sB + off);
    }
#pragma unroll
    for (int m = 0; m < 2; ++m)
#pragma unroll
      for (int n = 0; n < 4; ++n)
        acc[m][n] = __builtin_amdgcn_mfma_f32_16x16x32_f16(af[m], bf[n], acc[m][n],
                                                           0, 0, 0);
  }
#pragma unroll
  for (int m = 0; m < 2; ++m) {
#pragma unroll
    for (int j = 0; j < 4; ++j) {
      int row = brow + wv * 32 + m * 16 + (l >> 4) * 4 + j;
      if (row < N) {
        float di = dinv[row];
#pragma unroll
        for (int n = 0; n < 4; ++n) {
          float v = acc[m][n][j] * di;
          H[(size_t)row * 64 + n * 16 + lr] = __float2half_rn(v);
        }
      }
    }
  }
}

// One wave per node: out[i] = act(dinv[i]*(sum_edges hs[esrc] + hs[i]) + b)
// 4 groups x 16 lanes; 4x unroll (16 gathers in flight/wave); packed fp16
// accumulate into 8 independent half2 slots; fp32 from the reduce onward.
template <bool RELU, bool OUT_HALF>
__global__ __launch_bounds__(256) void agg_kernel(const __half* __restrict__ hs,
                                                  const int* __restrict__ rowptr,
                                                  const int* __restrict__ esrc,
                                                  const float* __restrict__ dinv,
                                                  const float* __restrict__ b,
                                                  void* __restrict__ outv, int N) {
  const int node = blockIdx.x * 4 + (threadIdx.x >> 6);
  if (node >= N) return;
  const int lane = threadIdx.x & 63;
  const int g = lane >> 4, cl = lane & 15;
  const unsigned int choff = (unsigned int)cl << 3;  // byte offset of 4-ch group
  const unsigned char* __restrict__ hb = (const unsigned char*)hs;
  const int beg = rowptr[node], end = rowptr[node + 1];
  __half2 aL[4] = {{0.f, 0.f}, {0.f, 0.f}, {0.f, 0.f}, {0.f, 0.f}};
  __half2 aH[4] = {{0.f, 0.f}, {0.f, 0.f}, {0.f, 0.f}, {0.f, 0.f}};
  int k = beg + g;
  for (; k + 12 < end; k += 16) {
    int s0 = esrc[k], s1 = esrc[k + 4], s2 = esrc[k + 8], s3 = esrc[k + 12];
    uint2 v0 = *reinterpret_cast<const uint2*>(hb + (((unsigned int)s0 << 7) + choff));
    uint2 v1 = *reinterpret_cast<const uint2*>(hb + (((unsigned int)s1 << 7) + choff));
    uint2 v2 = *reinterpret_cast<const uint2*>(hb + (((unsigned int)s2 << 7) + choff));
    uint2 v3 = *reinterpret_cast<const uint2*>(hb + (((unsigned int)s3 << 7) + choff));
    aL[0] = __hadd2(aL[0], *reinterpret_cast<__half2*>(&v0.x));
    aH[0] = __hadd2(aH[0], *reinterpret_cast<__half2*>(&v0.y));
    aL[1] = __hadd2(aL[1], *reinterpret_cast<__half2*>(&v1.x));
    aH[1] = __hadd2(aH[1], *reinterpret_cast<__half2*>(&v1.y));
    aL[2] = __hadd2(aL[2], *reinterpret_cast<__half2*>(&v2.x));
    aH[2] = __hadd2(aH[2], *reinterpret_cast<__half2*>(&v2.y));
    aL[3] = __hadd2(aL[3], *reinterpret_cast<__half2*>(&v3.x));
    aH[3] = __hadd2(aH[3], *reinterpret_cast<__half2*>(&v3.y));
  }
  for (; k < end; k += 4) {
    int s0 = esrc[k];
    uint2 v0 = *reinterpret_cast<const uint2*>(hb + (((unsigned int)s0 << 7) + choff));
    aL[0] = __hadd2(aL[0], *reinterpret_cast<__half2*>(&v0.x));
    aH[0] = __hadd2(aH[0], *reinterpret_cast<__half2*>(&v0.y));
  }
  float4 a0 = make_float4(0.f, 0.f, 0.f, 0.f);
#pragma unroll
  for (int u = 0; u < 4; ++u) {
    float2 fl = __half22float2(aL[u]);
    float2 fh = __half22float2(aH[u]);
    a0.x += fl.x; a0.y += fl.y; a0.z += fh.x; a0.w += fh.y;
  }
#pragma unroll
  for (int off = 16; off <= 32; off <<= 1) {
    a0.x += __shfl_xor(a0.x, off);
    a0.y += __shfl_xor(a0.y, off);
    a0.z += __shfl_xor(a0.z, off);
    a0.w += __shfl_xor(a0.w, off);
  }
  if (g == 0) {
    uint2 sv = *reinterpret_cast<const uint2*>(hb + (((unsigned int)node << 7) + choff));
    float2 s01 = __half22float2(*reinterpret_cast<__half2*>(&sv.x));
    float2 s23 = __half22float2(*reinterpret_cast<__half2*>(&sv.y));
    float di = dinv[node];
    float4 bb = reinterpret_cast<const float4*>(b)[cl];
    float4 r;
    r.x = (a0.x + s01.x) * di + bb.x;
    r.y = (a0.y + s01.y) * di + bb.y;
    r.z = (a0.z + s23.x) * di + bb.z;
    r.w = (a0.w + s23.y) * di + bb.w;
    if (RELU) {
      r.x = fmaxf(r.x, 0.f); r.y = fmaxf(r.y, 0.f);
      r.z = fmaxf(r.z, 0.f); r.w = fmaxf(r.w, 0.f);
    }
    if constexpr (OUT_HALF) {
      uint2 pk;
      pk.x = pack2(r.x, r.y);
      pk.y = pack2(r.z, r.w);
      reinterpret_cast<uint2*>(outv)[(size_t)node * 16 + cl] = pk;
    } else {
      reinterpret_cast<float4*>(outv)[(size_t)node * 16 + cl] = r;
    }
  }
}

extern "C" void kernel_launch(void* const* d_in, const int* in_sizes, int n_in,
                              void* d_out, int out_size, void* d_ws, size_t ws_size,
                              hipStream_t stream) {
  const float* x  = (const float*)d_in[0];
  const int*   ei = (const int*)d_in[1];
  const float* W1 = (const float*)d_in[2];
  const float* b1 = (const float*)d_in[3];
  const float* W2 = (const float*)d_in[4];
  const float* b2 = (const float*)d_in[5];
  const int N = in_sizes[0] / 128;
  const int E = in_sizes[1] / 2;
  const int* src = ei;
  const int* dst = ei + E;
  const int nb = (N + 127) >> 7;  // 782 buckets

  char* ws = (char*)d_ws;
  int*    bcursor = (int*)ws;                       // nb ints
  int*    bbase   = (int*)(ws + (1 << 19));         // nb ints   @ 512KB
  float*  dinv    = (float*)(ws + (1 << 20));       // N floats  @ 1MB
  int*    rowptr  = (int*)(ws + 3 * (1 << 19));     // N+1 ints  @ 1.5MB
  int*    esrc    = (int*)(ws + (1 << 21));         // E ints    @ 2MB   (6.4MB)
  int*    ebuck   = (int*)(ws + 9 * (1 << 20));     // nb*BCAP   @ 9MB   (12.8MB)
  __half* hs      = (__half*)(ws + 22 * (1 << 20)); // N*64 fp16 @ 22MB  (12.8MB)
  __half* y1h     = (__half*)(ws + 36 * (1 << 20)); // N*64 fp16 @ 36MB  (12.8MB)
  float*  out = (float*)d_out;

  // CSR build (shared by both layers)
  initcur_kernel<<<(nb + 255) / 256, 256, 0, stream>>>(bcursor, nb);
  chunksort_kernel<<<(E + CHUNK - 1) / CHUNK, 256, 0, stream>>>(src, dst, bcursor,
                                                                ebuck, E, nb);
  bscan_kernel<<<1, 1024, 0, stream>>>(bcursor, bbase, nb);
  bucketsort_kernel<<<nb, 256, 0, stream>>>(ebuck, bcursor, bbase, esrc, rowptr,
                                            dinv, N, E, nb);

  const int gemmGrid = (N + 127) / 128;
  const int aggGrid = (N + 3) / 4;
  // layer 1: hs1(fp16) -> hs ; y1(fp16, relu) -> y1h
  gemm_mfma<128, false><<<gemmGrid, 256, 0, stream>>>(x, W1, dinv, hs, N);
  agg_kernel<true, true><<<aggGrid, 256, 0, stream>>>(hs, rowptr, esrc, dinv, b1,
                                                      y1h, N);
  // layer 2: hs2(fp16) -> hs (reuse) ; y2(fp32) -> out
  gemm_mfma<64, true><<<gemmGrid, 256, 0, stream>>>(y1h, W2, dinv, hs, N);
  agg_kernel<false, false><<<aggGrid, 256, 0, stream>>>(hs, rowptr, esrc, dinv, b2,
                                                        out, N);
}

// Round 9
// 160.846 us; speedup vs baseline: 1.0994x; 1.0994x over previous
//
#include <hip/hip_runtime.h>
#include <hip/hip_fp16.h>

// GCN 2-layer forward. CSR via two-phase dst-sort (coalesced writes),
// MFMA fp16 GEMMs (fp32 accum), fp16 message tables, gather aggregation:
// 8 lanes x dwordx4 per edge-row (8 edges per wave-level VMEM instr).

#define CHUNK 4096
#define BCAP  4096
#define NB_PAD 1024

typedef _Float16 f16x8 __attribute__((ext_vector_type(8)));
typedef float f32x4 __attribute__((ext_vector_type(4)));

__device__ __forceinline__ unsigned int pack2(float a, float b) {
  __half2 h = __floats2half2_rn(a, b);
  return *reinterpret_cast<unsigned int*>(&h);
}
__device__ __forceinline__ __half2 h2add(__half2 a, __half2 b) {
  return __hadd2(a, b);
}
__device__ __forceinline__ __half2 bcast_h2(unsigned int u) {
  return *reinterpret_cast<__half2*>(&u);
}

__global__ __launch_bounds__(256) void initcur_kernel(int* __restrict__ bcursor,
                                                      int nb) {
  int i = blockIdx.x * 256 + threadIdx.x;
  if (i < nb) bcursor[i] = i * BCAP;
}

// Phase 1: group edges by bucket b = dst>>7 into bucket-major ebuck.
__global__ __launch_bounds__(256) void chunksort_kernel(
    const int* __restrict__ src, const int* __restrict__ dst,
    int* __restrict__ bcursor, int* __restrict__ ebuck, int nE, int nb) {
  __shared__ int hist[NB_PAD];
  __shared__ int loff[NB_PAD];
  __shared__ int gbase[NB_PAD];
  __shared__ int lcur[NB_PAD];
  __shared__ int part[256];
  __shared__ int srec[CHUNK];
  __shared__ int saddr[CHUNK];
  const int t = threadIdx.x;
  const int e0 = blockIdx.x * CHUNK;
  const int n = min(CHUNK, nE - e0);
#pragma unroll
  for (int i = t; i < NB_PAD; i += 256) hist[i] = 0;
  __syncthreads();
  for (int i = t; i < n; i += 256) atomicAdd(&hist[dst[e0 + i] >> 7], 1);
  __syncthreads();
  int h0 = hist[4 * t], h1 = hist[4 * t + 1], h2 = hist[4 * t + 2], h3 = hist[4 * t + 3];
  part[t] = h0 + h1 + h2 + h3;
  __syncthreads();
  for (int off = 1; off < 256; off <<= 1) {
    int v = (t >= off) ? part[t - off] : 0;
    __syncthreads();
    part[t] += v;
    __syncthreads();
  }
  int base = (t == 0) ? 0 : part[t - 1];
  loff[4 * t] = base;
  loff[4 * t + 1] = base + h0;
  loff[4 * t + 2] = base + h0 + h1;
  loff[4 * t + 3] = base + h0 + h1 + h2;
  __syncthreads();
  for (int b = t; b < nb; b += 256) {
    int c = hist[b];
    gbase[b] = c ? atomicAdd(&bcursor[b], c) : 0;
    lcur[b] = loff[b];
  }
  __syncthreads();
  for (int i = t; i < n; i += 256) {
    int d = dst[e0 + i];
    int b = d >> 7;
    int p = atomicAdd(&lcur[b], 1);
    srec[p] = src[e0 + i] | ((d & 127) << 17);
    saddr[p] = gbase[b] + (p - loff[b]);
  }
  __syncthreads();
  for (int i = t; i < n; i += 256) ebuck[saddr[i]] = srec[i];
}

__global__ __launch_bounds__(1024) void bscan_kernel(const int* __restrict__ bcursor,
                                                     int* __restrict__ bbase, int nb) {
  __shared__ int part[1024];
  const int t = threadIdx.x;
  int c = (t < nb) ? (bcursor[t] - t * BCAP) : 0;
  part[t] = c;
  __syncthreads();
  for (int off = 1; off < 1024; off <<= 1) {
    int v = (t >= off) ? part[t - off] : 0;
    __syncthreads();
    part[t] += v;
    __syncthreads();
  }
  if (t < nb) bbase[t] = part[t] - c;  // exclusive
}

// Phase 2: per-bucket counting sort -> fully dst-sorted esrc + rowptr + dinv.
__global__ __launch_bounds__(256) void bucketsort_kernel(
    const int* __restrict__ ebuck, const int* __restrict__ bcursor,
    const int* __restrict__ bbase, int* __restrict__ esrc,
    int* __restrict__ rowptr, float* __restrict__ dinv, int N, int E, int nb) {
  __shared__ int hist[128];
  __shared__ int sc[128];
  __shared__ int rowcur[128];
  __shared__ int ssrc[BCAP];
  const int t = threadIdx.x;
  const int bk = blockIdx.x;
  const int base = bk * BCAP;
  const int cnt = bcursor[bk] - base;
  const int gb = bbase[bk];
  if (t < 128) hist[t] = 0;
  __syncthreads();
  for (int i = t; i < cnt; i += 256)
    atomicAdd(&hist[(ebuck[base + i] >> 17) & 127], 1);
  __syncthreads();
  if (t < 128) sc[t] = hist[t];
  __syncthreads();
  for (int off = 1; off < 128; off <<= 1) {
    int v = 0;
    if (t < 128 && t >= off) v = sc[t - off];
    __syncthreads();
    if (t < 128) sc[t] += v;
    __syncthreads();
  }
  if (t < 128) {
    int excl = (t == 0) ? 0 : sc[t - 1];
    rowcur[t] = excl;
    int node = bk * 128 + t;
    if (node < N) {
      rowptr[node] = gb + excl;
      dinv[node] = rsqrtf((float)hist[t] + 1.0f);
    }
  }
  if (bk == nb - 1 && t == 0) rowptr[N] = E;
  __syncthreads();
  for (int i = t; i < cnt; i += 256) {
    int rec = ebuck[base + i];
    int p = atomicAdd(&rowcur[(rec >> 17) & 127], 1);
    ssrc[p] = rec & 0x1FFFF;
  }
  __syncthreads();
  for (int i = t; i < cnt; i += 256) esrc[gb + i] = ssrc[i];
}

// H[N,64](fp16) = (X[N,K] @ W[K,64]) * dinv[row], via mfma_f32_16x16x32_f16.
template <int K, bool IN_HALF>
__global__ __launch_bounds__(256) void gemm_mfma(const void* __restrict__ Xin,
                                                 const float* __restrict__ W,
                                                 const float* __restrict__ dinv,
                                                 __half* __restrict__ H, int N) {
  __shared__ __align__(16) unsigned char sA[128 * K * 2];
  __shared__ __align__(16) unsigned char sB[64 * K * 2];
  const int t = threadIdx.x;
  const int brow = blockIdx.x * 128;
  constexpr int CH = K / 8;
  for (int idx = t; idx < 128 * CH; idx += 256) {
    int r = idx / CH, c = idx - r * CH;
    int row = brow + r;
    if (row >= N) row = N - 1;
    unsigned int off = (unsigned int)((r * K + c * 8) * 2) ^ ((r & 7) << 4);
    uint4 pk;
    if constexpr (IN_HALF) {
      pk = *reinterpret_cast<const uint4*>((const __half*)Xin + (size_t)row * K + c * 8);
    } else {
      const float4* xp =
          reinterpret_cast<const float4*>((const float*)Xin + (size_t)row * K + c * 8);
      float4 f0 = xp[0], f1 = xp[1];
      pk.x = pack2(f0.x, f0.y);
      pk.y = pack2(f0.z, f0.w);
      pk.z = pack2(f1.x, f1.y);
      pk.w = pack2(f1.z, f1.w);
    }
    *reinterpret_cast<uint4*>(sA + off) = pk;
  }
  for (int idx = t; idx < K * 64; idx += 256) {
    int k = idx >> 6, n = idx & 63;
    __half h = __float2half_rn(W[idx]);
    unsigned int off = (unsigned int)((n * K + k) * 2) ^ ((n & 7) << 4);
    *reinterpret_cast<unsigned short*>(sB + off) =
        *reinterpret_cast<unsigned short*>(&h);
  }
  __syncthreads();

  const int wv = t >> 6, l = t & 63;
  const int lr = l & 15;
  const int lk = (l >> 4) * 8;
  f32x4 acc[2][4] = {};
#pragma unroll
  for (int ks = 0; ks < K / 32; ++ks) {
    f16x8 af[2], bf[4];
#pragma unroll
    for (int m = 0; m < 2; ++m) {
      int r = wv * 32 + m * 16 + lr;
      unsigned int off = (unsigned int)((r * K + ks * 32 + lk) * 2) ^ ((r & 7) << 4);
      af[m] = *reinterpret_cast<const f16x8*>(sA + off);
    }
#pragma unroll
    for (int n = 0; n < 4; ++n) {
      int cc = n * 16 + lr;
      unsigned int off = (unsigned int)((cc * K + ks * 32 + lk) * 2) ^ ((cc & 7) << 4);
      bf[n] = *reinterpret_cast<const f16x8*>(sB + off);
    }
#pragma unroll
    for (int m = 0; m < 2; ++m)
#pragma unroll
      for (int n = 0; n < 4; ++n)
        acc[m][n] = __builtin_amdgcn_mfma_f32_16x16x32_f16(af[m], bf[n], acc[m][n],
                                                           0, 0, 0);
  }
#pragma unroll
  for (int m = 0; m < 2; ++m) {
#pragma unroll
    for (int j = 0; j < 4; ++j) {
      int row = brow + wv * 32 + m * 16 + (l >> 4) * 4 + j;
      if (row < N) {
        float di = dinv[row];
#pragma unroll
        for (int n = 0; n < 4; ++n) {
          float v = acc[m][n][j] * di;
          H[(size_t)row * 64 + n * 16 + lr] = __float2half_rn(v);
        }
      }
    }
  }
}

// One wave per node: out[i] = act(dinv[i]*(sum_edges hs[esrc] + hs[i]) + b)
// 8 groups x 8 lanes x 16B (one dwordx4 row-slice per lane): one wave-level
// VMEM instruction gathers 8 edges. 2x unroll -> 16 edges (2KB) in flight.
template <bool RELU, bool OUT_HALF>
__global__ __launch_bounds__(256) void agg_kernel(const __half* __restrict__ hs,
                                                  const int* __restrict__ rowptr,
                                                  const int* __restrict__ esrc,
                                                  const float* __restrict__ dinv,
                                                  const float* __restrict__ b,
                                                  void* __restrict__ outv, int N) {
  const int node = blockIdx.x * 4 + (threadIdx.x >> 6);
  if (node >= N) return;
  const int lane = threadIdx.x & 63;
  const int g = lane >> 3;                            // 8 edge groups
  const int cl = lane & 7;                            // 16B slice of 128B row
  const unsigned int choff = (unsigned int)cl << 4;
  const unsigned char* __restrict__ hb = (const unsigned char*)hs;
  const int beg = rowptr[node], end = rowptr[node + 1];
  __half2 a0[4] = {{0.f, 0.f}, {0.f, 0.f}, {0.f, 0.f}, {0.f, 0.f}};
  __half2 a1[4] = {{0.f, 0.f}, {0.f, 0.f}, {0.f, 0.f}, {0.f, 0.f}};
  int k = beg + g;
  for (; k + 8 < end; k += 16) {
    int s0 = esrc[k], s1 = esrc[k + 8];
    uint4 v0 = *reinterpret_cast<const uint4*>(hb + (((unsigned int)s0 << 7) + choff));
    uint4 v1 = *reinterpret_cast<const uint4*>(hb + (((unsigned int)s1 << 7) + choff));
    a0[0] = h2add(a0[0], bcast_h2(v0.x));
    a0[1] = h2add(a0[1], bcast_h2(v0.y));
    a0[2] = h2add(a0[2], bcast_h2(v0.z));
    a0[3] = h2add(a0[3], bcast_h2(v0.w));
    a1[0] = h2add(a1[0], bcast_h2(v1.x));
    a1[1] = h2add(a1[1], bcast_h2(v1.y));
    a1[2] = h2add(a1[2], bcast_h2(v1.z));
    a1[3] = h2add(a1[3], bcast_h2(v1.w));
  }
  if (k < end) {
    int s0 = esrc[k];
    uint4 v0 = *reinterpret_cast<const uint4*>(hb + (((unsigned int)s0 << 7) + choff));
    a0[0] = h2add(a0[0], bcast_h2(v0.x));
    a0[1] = h2add(a0[1], bcast_h2(v0.y));
    a0[2] = h2add(a0[2], bcast_h2(v0.z));
    a0[3] = h2add(a0[3], bcast_h2(v0.w));
  }
#pragma unroll
  for (int r = 0; r < 4; ++r) a0[r] = h2add(a0[r], a1[r]);
  // reduce across the 8 groups (packed fp16): offsets 8,16,32
#pragma unroll
  for (int off = 8; off <= 32; off <<= 1) {
#pragma unroll
    for (int r = 0; r < 4; ++r) {
      int u = __shfl_xor(*reinterpret_cast<int*>(&a0[r]), off);
      a0[r] = h2add(a0[r], *reinterpret_cast<__half2*>(&u));
    }
  }
  if (g == 0) {
    uint4 sv = *reinterpret_cast<const uint4*>(hb + (((unsigned int)node << 7) + choff));
    float di = dinv[node];
    const float4* bv = reinterpret_cast<const float4*>(b);
    float4 b0 = bv[cl * 2], b1 = bv[cl * 2 + 1];
    float r[8];
#pragma unroll
    for (int q = 0; q < 4; ++q) {
      float2 av = __half22float2(a0[q]);
      float2 sf = __half22float2(bcast_h2((&sv.x)[q]));
      r[2 * q]     = (av.x + sf.x) * di;
      r[2 * q + 1] = (av.y + sf.y) * di;
    }
    r[0] += b0.x; r[1] += b0.y; r[2] += b0.z; r[3] += b0.w;
    r[4] += b1.x; r[5] += b1.y; r[6] += b1.z; r[7] += b1.w;
    if (RELU) {
#pragma unroll
      for (int q = 0; q < 8; ++q) r[q] = fmaxf(r[q], 0.f);
    }
    if constexpr (OUT_HALF) {
      uint4 pk;
      pk.x = pack2(r[0], r[1]);
      pk.y = pack2(r[2], r[3]);
      pk.z = pack2(r[4], r[5]);
      pk.w = pack2(r[6], r[7]);
      reinterpret_cast<uint4*>(outv)[(size_t)node * 8 + cl] = pk;
    } else {
      float4* ov = reinterpret_cast<float4*>(outv);
      ov[(size_t)node * 16 + cl * 2]     = make_float4(r[0], r[1], r[2], r[3]);
      ov[(size_t)node * 16 + cl * 2 + 1] = make_float4(r[4], r[5], r[6], r[7]);
    }
  }
}

extern "C" void kernel_launch(void* const* d_in, const int* in_sizes, int n_in,
                              void* d_out, int out_size, void* d_ws, size_t ws_size,
                              hipStream_t stream) {
  const float* x  = (const float*)d_in[0];
  const int*   ei = (const int*)d_in[1];
  const float* W1 = (const float*)d_in[2];
  const float* b1 = (const float*)d_in[3];
  const float* W2 = (const float*)d_in[4];
  const float* b2 = (const float*)d_in[5];
  const int N = in_sizes[0] / 128;
  const int E = in_sizes[1] / 2;
  const int* src = ei;
  const int* dst = ei + E;
  const int nb = (N + 127) >> 7;  // 782 buckets

  char* ws = (char*)d_ws;
  int*    bcursor = (int*)ws;                       // nb ints
  int*    bbase   = (int*)(ws + (1 << 19));         // nb ints   @ 512KB
  float*  dinv    = (float*)(ws + (1 << 20));       // N floats  @ 1MB
  int*    rowptr  = (int*)(ws + 3 * (1 << 19));     // N+1 ints  @ 1.5MB
  int*    esrc    = (int*)(ws + (1 << 21));         // E ints    @ 2MB   (6.4MB)
  int*    ebuck   = (int*)(ws + 9 * (1 << 20));     // nb*BCAP   @ 9MB   (12.8MB)
  __half* hs      = (__half*)(ws + 22 * (1 << 20)); // N*64 fp16 @ 22MB  (12.8MB)
  __half* y1h     = (__half*)(ws + 36 * (1 << 20)); // N*64 fp16 @ 36MB  (12.8MB)
  float*  out = (float*)d_out;

  // CSR build (shared by both layers)
  initcur_kernel<<<(nb + 255) / 256, 256, 0, stream>>>(bcursor, nb);
  chunksort_kernel<<<(E + CHUNK - 1) / CHUNK, 256, 0, stream>>>(src, dst, bcursor,
                                                                ebuck, E, nb);
  bscan_kernel<<<1, 1024, 0, stream>>>(bcursor, bbase, nb);
  bucketsort_kernel<<<nb, 256, 0, stream>>>(ebuck, bcursor, bbase, esrc, rowptr,
                                            dinv, N, E, nb);

  const int gemmGrid = (N + 127) / 128;
  const int aggGrid = (N + 3) / 4;
  // layer 1: hs1(fp16) -> hs ; y1(fp16, relu) -> y1h
  gemm_mfma<128, false><<<gemmGrid, 256, 0, stream>>>(x, W1, dinv, hs, N);
  agg_kernel<true, true><<<aggGrid, 256, 0, stream>>>(hs, rowptr, esrc, dinv, b1,
                                                      y1h, N);
  // layer 2: hs2(fp16) -> hs (reuse) ; y2(fp32) -> out
  gemm_mfma<64, true><<<gemmGrid, 256, 0, stream>>>(y1h, W2, dinv, hs, N);
  agg_kernel<false, false><<<aggGrid, 256, 0, stream>>>(hs, rowptr, esrc, dinv, b2,
                                                        out, N);
}

// Round 10
// 142.056 us; speedup vs baseline: 1.2448x; 1.1323x over previous
//
#include <hip/hip_runtime.h>
#include <hip/hip_fp16.h>

// GCN 2-layer forward. CSR via two-phase dst-sort (coalesced writes),
// MFMA fp16 GEMMs (fp32 accum), fp16 message tables, gather aggregation:
// 4 nodes per wave x (2 groups x 8 lanes x 16B), unroll-4 -> 4 independent
// wave-level gather instrs in flight (8 edges each).

#define CHUNK 4096
#define BCAP  4096
#define NB_PAD 1024

typedef _Float16 f16x8 __attribute__((ext_vector_type(8)));
typedef float f32x4 __attribute__((ext_vector_type(4)));

__device__ __forceinline__ unsigned int pack2(float a, float b) {
  __half2 h = __floats2half2_rn(a, b);
  return *reinterpret_cast<unsigned int*>(&h);
}
__device__ __forceinline__ __half2 h2add(__half2 a, __half2 b) {
  return __hadd2(a, b);
}
__device__ __forceinline__ __half2 bcast_h2(unsigned int u) {
  return *reinterpret_cast<__half2*>(&u);
}

__global__ __launch_bounds__(256) void initcur_kernel(int* __restrict__ bcursor,
                                                      int nb) {
  int i = blockIdx.x * 256 + threadIdx.x;
  if (i < nb) bcursor[i] = i * BCAP;
}

// Phase 1: group edges by bucket b = dst>>7 into bucket-major ebuck.
__global__ __launch_bounds__(256) void chunksort_kernel(
    const int* __restrict__ src, const int* __restrict__ dst,
    int* __restrict__ bcursor, int* __restrict__ ebuck, int nE, int nb) {
  __shared__ int hist[NB_PAD];
  __shared__ int loff[NB_PAD];
  __shared__ int gbase[NB_PAD];
  __shared__ int lcur[NB_PAD];
  __shared__ int part[256];
  __shared__ int srec[CHUNK];
  __shared__ int saddr[CHUNK];
  const int t = threadIdx.x;
  const int e0 = blockIdx.x * CHUNK;
  const int n = min(CHUNK, nE - e0);
#pragma unroll
  for (int i = t; i < NB_PAD; i += 256) hist[i] = 0;
  __syncthreads();
  for (int i = t; i < n; i += 256) atomicAdd(&hist[dst[e0 + i] >> 7], 1);
  __syncthreads();
  int h0 = hist[4 * t], h1 = hist[4 * t + 1], h2 = hist[4 * t + 2], h3 = hist[4 * t + 3];
  part[t] = h0 + h1 + h2 + h3;
  __syncthreads();
  for (int off = 1; off < 256; off <<= 1) {
    int v = (t >= off) ? part[t - off] : 0;
    __syncthreads();
    part[t] += v;
    __syncthreads();
  }
  int base = (t == 0) ? 0 : part[t - 1];
  loff[4 * t] = base;
  loff[4 * t + 1] = base + h0;
  loff[4 * t + 2] = base + h0 + h1;
  loff[4 * t + 3] = base + h0 + h1 + h2;
  __syncthreads();
  for (int b = t; b < nb; b += 256) {
    int c = hist[b];
    gbase[b] = c ? atomicAdd(&bcursor[b], c) : 0;
    lcur[b] = loff[b];
  }
  __syncthreads();
  for (int i = t; i < n; i += 256) {
    int d = dst[e0 + i];
    int b = d >> 7;
    int p = atomicAdd(&lcur[b], 1);
    srec[p] = src[e0 + i] | ((d & 127) << 17);
    saddr[p] = gbase[b] + (p - loff[b]);
  }
  __syncthreads();
  for (int i = t; i < n; i += 256) ebuck[saddr[i]] = srec[i];
}

__global__ __launch_bounds__(1024) void bscan_kernel(const int* __restrict__ bcursor,
                                                     int* __restrict__ bbase, int nb) {
  __shared__ int part[1024];
  const int t = threadIdx.x;
  int c = (t < nb) ? (bcursor[t] - t * BCAP) : 0;
  part[t] = c;
  __syncthreads();
  for (int off = 1; off < 1024; off <<= 1) {
    int v = (t >= off) ? part[t - off] : 0;
    __syncthreads();
    part[t] += v;
    __syncthreads();
  }
  if (t < nb) bbase[t] = part[t] - c;  // exclusive
}

// Phase 2: per-bucket counting sort -> fully dst-sorted esrc + rowptr + dinv.
__global__ __launch_bounds__(256) void bucketsort_kernel(
    const int* __restrict__ ebuck, const int* __restrict__ bcursor,
    const int* __restrict__ bbase, int* __restrict__ esrc,
    int* __restrict__ rowptr, float* __restrict__ dinv, int N, int E, int nb) {
  __shared__ int hist[128];
  __shared__ int sc[128];
  __shared__ int rowcur[128];
  __shared__ int ssrc[BCAP];
  const int t = threadIdx.x;
  const int bk = blockIdx.x;
  const int base = bk * BCAP;
  const int cnt = bcursor[bk] - base;
  const int gb = bbase[bk];
  if (t < 128) hist[t] = 0;
  __syncthreads();
  for (int i = t; i < cnt; i += 256)
    atomicAdd(&hist[(ebuck[base + i] >> 17) & 127], 1);
  __syncthreads();
  if (t < 128) sc[t] = hist[t];
  __syncthreads();
  for (int off = 1; off < 128; off <<= 1) {
    int v = 0;
    if (t < 128 && t >= off) v = sc[t - off];
    __syncthreads();
    if (t < 128) sc[t] += v;
    __syncthreads();
  }
  if (t < 128) {
    int excl = (t == 0) ? 0 : sc[t - 1];
    rowcur[t] = excl;
    int node = bk * 128 + t;
    if (node < N) {
      rowptr[node] = gb + excl;
      dinv[node] = rsqrtf((float)hist[t] + 1.0f);
    }
  }
  if (bk == nb - 1 && t == 0) rowptr[N] = E;
  __syncthreads();
  for (int i = t; i < cnt; i += 256) {
    int rec = ebuck[base + i];
    int p = atomicAdd(&rowcur[(rec >> 17) & 127], 1);
    ssrc[p] = rec & 0x1FFFF;
  }
  __syncthreads();
  for (int i = t; i < cnt; i += 256) esrc[gb + i] = ssrc[i];
}

// H[N,64](fp16) = (X[N,K] @ W[K,64]) * dinv[row], via mfma_f32_16x16x32_f16.
template <int K, bool IN_HALF>
__global__ __launch_bounds__(256) void gemm_mfma(const void* __restrict__ Xin,
                                                 const float* __restrict__ W,
                                                 const float* __restrict__ dinv,
                                                 __half* __restrict__ H, int N) {
  __shared__ __align__(16) unsigned char sA[128 * K * 2];
  __shared__ __align__(16) unsigned char sB[64 * K * 2];
  const int t = threadIdx.x;
  const int brow = blockIdx.x * 128;
  constexpr int CH = K / 8;
  for (int idx = t; idx < 128 * CH; idx += 256) {
    int r = idx / CH, c = idx - r * CH;
    int row = brow + r;
    if (row >= N) row = N - 1;
    unsigned int off = (unsigned int)((r * K + c * 8) * 2) ^ ((r & 7) << 4);
    uint4 pk;
    if constexpr (IN_HALF) {
      pk = *reinterpret_cast<const uint4*>((const __half*)Xin + (size_t)row * K + c * 8);
    } else {
      const float4* xp =
          reinterpret_cast<const float4*>((const float*)Xin + (size_t)row * K + c * 8);
      float4 f0 = xp[0], f1 = xp[1];
      pk.x = pack2(f0.x, f0.y);
      pk.y = pack2(f0.z, f0.w);
      pk.z = pack2(f1.x, f1.y);
      pk.w = pack2(f1.z, f1.w);
    }
    *reinterpret_cast<uint4*>(sA + off) = pk;
  }
  for (int idx = t; idx < K * 64; idx += 256) {
    int k = idx >> 6, n = idx & 63;
    __half h = __float2half_rn(W[idx]);
    unsigned int off = (unsigned int)((n * K + k) * 2) ^ ((n & 7) << 4);
    *reinterpret_cast<unsigned short*>(sB + off) =
        *reinterpret_cast<unsigned short*>(&h);
  }
  __syncthreads();

  const int wv = t >> 6, l = t & 63;
  const int lr = l & 15;
  const int lk = (l >> 4) * 8;
  f32x4 acc[2][4] = {};
#pragma unroll
  for (int ks = 0; ks < K / 32; ++ks) {
    f16x8 af[2], bf[4];
#pragma unroll
    for (int m = 0; m < 2; ++m) {
      int r = wv * 32 + m * 16 + lr;
      unsigned int off = (unsigned int)((r * K + ks * 32 + lk) * 2) ^ ((r & 7) << 4);
      af[m] = *reinterpret_cast<const f16x8*>(sA + off);
    }
#pragma unroll
    for (int n = 0; n < 4; ++n) {
      int cc = n * 16 + lr;
      unsigned int off = (unsigned int)((cc * K + ks * 32 + lk) * 2) ^ ((cc & 7) << 4);
      bf[n] = *reinterpret_cast<const f16x8*>(sB + off);
    }
#pragma unroll
    for (int m = 0; m < 2; ++m)
#pragma unroll
      for (int n = 0; n < 4; ++n)
        acc[m][n] = __builtin_amdgcn_mfma_f32_16x16x32_f16(af[m], bf[n], acc[m][n],
                                                           0, 0, 0);
  }
#pragma unroll
  for (int m = 0; m < 2; ++m) {
#pragma unroll
    for (int j = 0; j < 4; ++j) {
      int row = brow + wv * 32 + m * 16 + (l >> 4) * 4 + j;
      if (row < N) {
        float di = dinv[row];
#pragma unroll
        for (int n = 0; n < 4; ++n) {
          float v = acc[m][n][j] * di;
          H[(size_t)row * 64 + n * 16 + lr] = __float2half_rn(v);
        }
      }
    }
  }
}

// 4 nodes per wave: nid=lane>>4 (node), g=(lane>>3)&1 (edge group),
// cl=lane&7 (16B slice of 128B row). Per iteration: 4 wave-level uint4
// gathers (8 edges each, 2 per node), 4 independent streams -> ~4 VMEM
// instrs in flight. Reduce = single shuffle (offset 8). Masked tail.
template <bool RELU, bool OUT_HALF>
__global__ __launch_bounds__(256) void agg_kernel(const __half* __restrict__ hs,
                                                  const int* __restrict__ rowptr,
                                                  const int* __restrict__ esrc,
                                                  const float* __restrict__ dinv,
                                                  const float* __restrict__ b,
                                                  void* __restrict__ outv, int N) {
  const int wv = threadIdx.x >> 6;
  const int lane = threadIdx.x & 63;
  const int nid = lane >> 4;
  const int g = (lane >> 3) & 1;
  const int cl = lane & 7;
  const int node = blockIdx.x * 16 + wv * 4 + nid;
  const unsigned int choff = (unsigned int)cl << 4;
  const unsigned char* __restrict__ hb = (const unsigned char*)hs;
  int beg = 0, end = 0;
  if (node < N) {
    beg = rowptr[node];
    end = rowptr[node + 1];
  }
  __half2 accA[4] = {{0.f, 0.f}, {0.f, 0.f}, {0.f, 0.f}, {0.f, 0.f}};
  __half2 accB[4] = {{0.f, 0.f}, {0.f, 0.f}, {0.f, 0.f}, {0.f, 0.f}};
  int k = beg + g;
  while (k < end) {
    int s0 = esrc[min(k,     end - 1)];
    int s1 = esrc[min(k + 2, end - 1)];
    int s2 = esrc[min(k + 4, end - 1)];
    int s3 = esrc[min(k + 6, end - 1)];
    uint4 v0 = *reinterpret_cast<const uint4*>(hb + (((unsigned int)s0 << 7) + choff));
    uint4 v1 = *reinterpret_cast<const uint4*>(hb + (((unsigned int)s1 << 7) + choff));
    uint4 v2 = *reinterpret_cast<const uint4*>(hb + (((unsigned int)s2 << 7) + choff));
    uint4 v3 = *reinterpret_cast<const uint4*>(hb + (((unsigned int)s3 << 7) + choff));
    {
      accA[0] = h2add(accA[0], bcast_h2(v0.x));
      accA[1] = h2add(accA[1], bcast_h2(v0.y));
      accA[2] = h2add(accA[2], bcast_h2(v0.z));
      accA[3] = h2add(accA[3], bcast_h2(v0.w));
    }
    if (k + 2 < end) {
      accB[0] = h2add(accB[0], bcast_h2(v1.x));
      accB[1] = h2add(accB[1], bcast_h2(v1.y));
      accB[2] = h2add(accB[2], bcast_h2(v1.z));
      accB[3] = h2add(accB[3], bcast_h2(v1.w));
    }
    if (k + 4 < end) {
      accA[0] = h2add(accA[0], bcast_h2(v2.x));
      accA[1] = h2add(accA[1], bcast_h2(v2.y));
      accA[2] = h2add(accA[2], bcast_h2(v2.z));
      accA[3] = h2add(accA[3], bcast_h2(v2.w));
    }
    if (k + 6 < end) {
      accB[0] = h2add(accB[0], bcast_h2(v3.x));
      accB[1] = h2add(accB[1], bcast_h2(v3.y));
      accB[2] = h2add(accB[2], bcast_h2(v3.z));
      accB[3] = h2add(accB[3], bcast_h2(v3.w));
    }
    k += 8;
  }
#pragma unroll
  for (int r = 0; r < 4; ++r) accA[r] = h2add(accA[r], accB[r]);
  // reduce across the 2 groups (lanes g=0 and g=1): offset 8
#pragma unroll
  for (int r = 0; r < 4; ++r) {
    int u = __shfl_xor(*reinterpret_cast<int*>(&accA[r]), 8);
    accA[r] = h2add(accA[r], *reinterpret_cast<__half2*>(&u));
  }
  if (g == 0 && node < N) {
    uint4 sv = *reinterpret_cast<const uint4*>(hb + (((unsigned int)node << 7) + choff));
    float di = dinv[node];
    const float4* bv = reinterpret_cast<const float4*>(b);
    float4 b0 = bv[cl * 2], b1 = bv[cl * 2 + 1];
    float r[8];
#pragma unroll
    for (int q = 0; q < 4; ++q) {
      float2 av = __half22float2(accA[q]);
      float2 sf = __half22float2(bcast_h2((&sv.x)[q]));
      r[2 * q]     = (av.x + sf.x) * di;
      r[2 * q + 1] = (av.y + sf.y) * di;
    }
    r[0] += b0.x; r[1] += b0.y; r[2] += b0.z; r[3] += b0.w;
    r[4] += b1.x; r[5] += b1.y; r[6] += b1.z; r[7] += b1.w;
    if (RELU) {
#pragma unroll
      for (int q = 0; q < 8; ++q) r[q] = fmaxf(r[q], 0.f);
    }
    if constexpr (OUT_HALF) {
      uint4 pk;
      pk.x = pack2(r[0], r[1]);
      pk.y = pack2(r[2], r[3]);
      pk.z = pack2(r[4], r[5]);
      pk.w = pack2(r[6], r[7]);
      reinterpret_cast<uint4*>(outv)[(size_t)node * 8 + cl] = pk;
    } else {
      float4* ov = reinterpret_cast<float4*>(outv);
      ov[(size_t)node * 16 + cl * 2]     = make_float4(r[0], r[1], r[2], r[3]);
      ov[(size_t)node * 16 + cl * 2 + 1] = make_float4(r[4], r[5], r[6], r[7]);
    }
  }
}

extern "C" void kernel_launch(void* const* d_in, const int* in_sizes, int n_in,
                              void* d_out, int out_size, void* d_ws, size_t ws_size,
                              hipStream_t stream) {
  const float* x  = (const float*)d_in[0];
  const int*   ei = (const int*)d_in[1];
  const float* W1 = (const float*)d_in[2];
  const float* b1 = (const float*)d_in[3];
  const float* W2 = (const float*)d_in[4];
  const float* b2 = (const float*)d_in[5];
  const int N = in_sizes[0] / 128;
  const int E = in_sizes[1] / 2;
  const int* src = ei;
  const int* dst = ei + E;
  const int nb = (N + 127) >> 7;  // 782 buckets

  char* ws = (char*)d_ws;
  int*    bcursor = (int*)ws;                       // nb ints
  int*    bbase   = (int*)(ws + (1 << 19));         // nb ints   @ 512KB
  float*  dinv    = (float*)(ws + (1 << 20));       // N floats  @ 1MB
  int*    rowptr  = (int*)(ws + 3 * (1 << 19));     // N+1 ints  @ 1.5MB
  int*    esrc    = (int*)(ws + (1 << 21));         // E ints    @ 2MB   (6.4MB)
  int*    ebuck   = (int*)(ws + 9 * (1 << 20));     // nb*BCAP   @ 9MB   (12.8MB)
  __half* hs      = (__half*)(ws + 22 * (1 << 20)); // N*64 fp16 @ 22MB  (12.8MB)
  __half* y1h     = (__half*)(ws + 36 * (1 << 20)); // N*64 fp16 @ 36MB  (12.8MB)
  float*  out = (float*)d_out;

  // CSR build (shared by both layers)
  initcur_kernel<<<(nb + 255) / 256, 256, 0, stream>>>(bcursor, nb);
  chunksort_kernel<<<(E + CHUNK - 1) / CHUNK, 256, 0, stream>>>(src, dst, bcursor,
                                                                ebuck, E, nb);
  bscan_kernel<<<1, 1024, 0, stream>>>(bcursor, bbase, nb);
  bucketsort_kernel<<<nb, 256, 0, stream>>>(ebuck, bcursor, bbase, esrc, rowptr,
                                            dinv, N, E, nb);

  const int gemmGrid = (N + 127) / 128;
  const int aggGrid = (N + 15) / 16;
  // layer 1: hs1(fp16) -> hs ; y1(fp16, relu) -> y1h
  gemm_mfma<128, false><<<gemmGrid, 256, 0, stream>>>(x, W1, dinv, hs, N);
  agg_kernel<true, true><<<aggGrid, 256, 0, stream>>>(hs, rowptr, esrc, dinv, b1,
                                                      y1h, N);
  // layer 2: hs2(fp16) -> hs (reuse) ; y2(fp32) -> out
  gemm_mfma<64, true><<<gemmGrid, 256, 0, stream>>>(y1h, W2, dinv, hs, N);
  agg_kernel<false, false><<<aggGrid, 256, 0, stream>>>(hs, rowptr, esrc, dinv, b2,
                                                        out, N);
}